// Round 9
// baseline (246.714 us; speedup 1.0000x reference)
//
#include <hip/hip_runtime.h>

#define BATCH 16384
#define KDIM  8192
#define ODIM  32
#define SK    4                   // split-K across blocks
#define KSLICE (KDIM / SK)        // 2048 k per block
#define NWAVE 4
#define THREADS (NWAVE * 64)
#define KT    32                  // k per LDS tile
#define NTILE (KSLICE / KT)       // 64 tiles
#define LP    36                  // padded row stride (floats): 16B-aligned, uniform banks

// ---------------------------------------------------------------------------
// Prep: bwT[k][o] = sign(w[o][k]) as +-1.0f/0, + per-block partial sum |w|
// ---------------------------------------------------------------------------
__global__ void prep_kernel(const float* __restrict__ w,
                            float* __restrict__ bwT,
                            float* __restrict__ partial) {
    int idx = blockIdx.x * 256 + threadIdx.x;     // coalesced over 32*8192
    int o = idx >> 13;
    int k = idx & (KDIM - 1);
    float v = w[idx];
    float s = (v > 0.f) ? 1.f : ((v < 0.f) ? -1.f : 0.f);
    bwT[(size_t)k * ODIM + o] = s;

    float a = fabsf(v);
    #pragma unroll
    for (int off = 32; off; off >>= 1) a += __shfl_down(a, off, 64);
    __shared__ float red[4];
    int lane = threadIdx.x & 63, wv = threadIdx.x >> 6;
    if (lane == 0) red[wv] = a;
    __syncthreads();
    if (threadIdx.x == 0)
        partial[blockIdx.x] = (red[0] + red[1]) + (red[2] + red[3]);
}

// ---------------------------------------------------------------------------
// Main: 1024 blocks x 256 thr, 8 blocks/CU (32 waves/CU). Tile = 64 rows x
// 32 k, double-buffered padded LDS, 1 barrier pair per tile (256 FMAs/wave
// between barriers). lane = row -> weights wave-uniform (readfirstlane) ->
// scalar s_load. kb = bid&3: each XCD owns one 256KB weight slice (L2-hot).
// Split-K=4 partials, no atomics, deterministic.
// ---------------------------------------------------------------------------
__global__ __launch_bounds__(THREADS, 8)
void main_kernel(const float* __restrict__ x,
                 const float* __restrict__ bwT,
                 float* __restrict__ pout) {
    __shared__ union {
        float buf[2][64][LP];     // 18432 B
        float part[2][ODIM][65];  // 16640 B
    } sm;

    const int tid  = threadIdx.x;
    const int wv   = __builtin_amdgcn_readfirstlane(tid >> 6);  // MUST be SGPR
    const int lane = tid & 63;
    const int kb   = blockIdx.x & 3;           // XCD-locked weight slice
    const int rb   = blockIdx.x >> 2;          // 0..255
    const size_t rowbase = (size_t)rb * 64;
    const int kbase = kb * KSLICE;

    // staging: thread t writes float4 at (row = t>>3, q = t&7) and (+32 rows)
    const int sr = tid >> 3;
    const int sq = tid & 7;
    const float* __restrict__ xg0 = x + (rowbase + sr) * (size_t)KDIM + kbase + 4 * sq;
    const float* __restrict__ xg1 = xg0 + (size_t)32 * KDIM;

    float acc[ODIM];
    #pragma unroll
    for (int o = 0; o < ODIM; ++o) acc[o] = 0.f;

    // prologue: tile 0 -> buf0
    float4 v0 = *(const float4*)xg0;
    float4 v1 = *(const float4*)xg1;
    *(float4*)&sm.buf[0][sr][4 * sq]      = v0;
    *(float4*)&sm.buf[0][sr + 32][4 * sq] = v1;

    const float* __restrict__ wb = bwT + (size_t)(kbase + wv * 8) * ODIM;

    for (int t = 0; t < NTILE; ++t) {
        float4 n0, n1;
        if (t + 1 < NTILE) {
            n0 = *(const float4*)(xg0 + (t + 1) * KT);
            n1 = *(const float4*)(xg1 + (t + 1) * KT);
        }

        __syncthreads();   // buf[t&1] fully written; buf[(t+1)&1] free

        // this wave's 8 k's of the tile: two structural-floor ds_read_b128
        const float4 xk0 = *(const float4*)&sm.buf[t & 1][lane][wv * 8];
        const float4 xk1 = *(const float4*)&sm.buf[t & 1][lane][wv * 8 + 4];

        if (t + 1 < NTILE) {
            *(float4*)&sm.buf[(t + 1) & 1][sr][4 * sq]      = n0;
            *(float4*)&sm.buf[(t + 1) & 1][sr + 32][4 * sq] = n1;
        }

        const float xs[8] = {xk0.x, xk0.y, xk0.z, xk0.w,
                             xk1.x, xk1.y, xk1.z, xk1.w};
        const float* __restrict__ wt = wb + (size_t)t * KT * ODIM;
        #pragma unroll
        for (int kk = 0; kk < 8; ++kk) {
            const float* __restrict__ wo = wt + kk * ODIM;   // wave-uniform
            #pragma unroll
            for (int o = 0; o < ODIM; ++o)
                acc[o] = fmaf(xs[kk], wo[o], acc[o]);
        }
    }

    // two-phase cross-wave reduce (fits union)
    __syncthreads();
    if (wv < 2) {
        #pragma unroll
        for (int o = 0; o < ODIM; ++o) sm.part[wv][o][lane] = acc[o];
    }
    __syncthreads();
    if (wv >= 2) {
        #pragma unroll
        for (int o = 0; o < ODIM; ++o) sm.part[wv - 2][o][lane] += acc[o];
    }
    __syncthreads();

    float* __restrict__ pb = pout + ((size_t)kb * BATCH + rowbase) * ODIM;
    #pragma unroll
    for (int i = 0; i < 8; ++i) {
        int j = tid + THREADS * i;        // j = r*32 + o, fully coalesced
        int r = j >> 5, o = j & 31;
        pb[j] = sm.part[0][o][r] + sm.part[1][o][r];
    }
}

// ---------------------------------------------------------------------------
// Final: recompute scale from the 1024 |w| partials (L2-hot, deterministic),
// then out = (p0+p1+p2+p3) * scale. Grid 512 x 256.
// ---------------------------------------------------------------------------
__global__ void reduce_kernel(const float* __restrict__ pout,
                              const float* __restrict__ partial,
                              float* __restrict__ out) {
    const int t = threadIdx.x;
    float a = (partial[t] + partial[t + 256]) + (partial[t + 512] + partial[t + 768]);
    #pragma unroll
    for (int off = 32; off; off >>= 1) a += __shfl_down(a, off, 64);
    __shared__ float red[4];
    __shared__ float sbc;
    if ((t & 63) == 0) red[t >> 6] = a;
    __syncthreads();
    if (t == 0)
        sbc = ((red[0] + red[1]) + (red[2] + red[3])) / (float)(ODIM * KDIM);
    __syncthreads();
    const float s = sbc;

    const int STRIDE = BATCH * ODIM / 4;          // float4 per split slice
    int i = blockIdx.x * 256 + t;
    const float4* p = (const float4*)pout;
    float4 A = p[i], B = p[i + STRIDE], C = p[i + 2 * STRIDE], D = p[i + 3 * STRIDE];
    float4 r;
    r.x = ((A.x + B.x) + (C.x + D.x)) * s;
    r.y = ((A.y + B.y) + (C.y + D.y)) * s;
    r.z = ((A.z + B.z) + (C.z + D.z)) * s;
    r.w = ((A.w + B.w) + (C.w + D.w)) * s;
    ((float4*)out)[i] = r;
}

// ---------------------------------------------------------------------------
extern "C" void kernel_launch(void* const* d_in, const int* in_sizes, int n_in,
                              void* d_out, int out_size, void* d_ws, size_t ws_size,
                              hipStream_t stream) {
    const float* x = (const float*)d_in[0];
    const float* w = (const float*)d_in[1];
    float* out = (float*)d_out;

    float* wsf     = (float*)d_ws;
    float* partial = wsf;                       // 1024 floats
    float* bwT     = wsf + 1024;                // 262144 floats (1 MiB), [k][o]
    float* pout    = wsf + 1024 + ODIM * KDIM;  // SK * 524288 floats (8 MiB)

    prep_kernel<<<1024, 256, 0, stream>>>(w, bwT, partial);
    main_kernel<<<256 * SK, THREADS, 0, stream>>>(x, bwT, pout);
    reduce_kernel<<<BATCH * ODIM / 4 / 256, 256, 0, stream>>>(pout, partial, out);
}

// Round 10
// 181.176 us; speedup vs baseline: 1.3617x; 1.3617x over previous
//
#include <hip/hip_runtime.h>

#define BATCH 16384
#define KDIM  8192
#define ODIM  32
#define SK    8                   // split-K across blocks (grid 2048 -> 8 blocks/CU)
#define KSLICE (KDIM / SK)        // 1024 k per block
#define NWAVE 4
#define THREADS (NWAVE * 64)
#define KT    32                  // k per LDS tile
#define NTILE (KSLICE / KT)       // 32 tiles
#define LP    36                  // padded row stride (floats): 16B-aligned, uniform banks

// ---------------------------------------------------------------------------
// Prep: bwT[k][o] = sign(w[o][k]) as +-1.0f/0, + per-block partial sum |w|
// ---------------------------------------------------------------------------
__global__ void prep_kernel(const float* __restrict__ w,
                            float* __restrict__ bwT,
                            float* __restrict__ partial) {
    int idx = blockIdx.x * 256 + threadIdx.x;     // coalesced over 32*8192
    int o = idx >> 13;
    int k = idx & (KDIM - 1);
    float v = w[idx];
    float s = (v > 0.f) ? 1.f : ((v < 0.f) ? -1.f : 0.f);
    bwT[(size_t)k * ODIM + o] = s;

    float a = fabsf(v);
    #pragma unroll
    for (int off = 32; off; off >>= 1) a += __shfl_down(a, off, 64);
    __shared__ float red[4];
    int lane = threadIdx.x & 63, wv = threadIdx.x >> 6;
    if (lane == 0) red[wv] = a;
    __syncthreads();
    if (threadIdx.x == 0)
        partial[blockIdx.x] = (red[0] + red[1]) + (red[2] + red[3]);
}

// ---------------------------------------------------------------------------
// Main: 2048 blocks x 256 thr = 8 blocks/CU (32 waves/CU — occupancy is the
// proven lever; grid must SUPPLY it, not just launch_bounds). Tile = 64 rows
// x 32 k, double-buffered padded LDS, 1 barrier pair per tile (256 FMAs/wave
// between barriers). lane = row -> weights wave-uniform (readfirstlane) ->
// scalar s_load. kb = bid&7: each of 8 XCDs owns one 128KB weight slice.
// Split-K=8 partials, no atomics, deterministic.
// ---------------------------------------------------------------------------
__global__ __launch_bounds__(THREADS, 8)
void main_kernel(const float* __restrict__ x,
                 const float* __restrict__ bwT,
                 float* __restrict__ pout) {
    __shared__ union {
        float buf[2][64][LP];     // 18432 B
        float part[2][ODIM][65];  // 16640 B
    } sm;

    const int tid  = threadIdx.x;
    const int wv   = __builtin_amdgcn_readfirstlane(tid >> 6);  // MUST be SGPR
    const int lane = tid & 63;
    const int kb   = blockIdx.x & 7;           // XCD-locked weight slice
    const int rb   = blockIdx.x >> 3;          // 0..255
    const size_t rowbase = (size_t)rb * 64;
    const int kbase = kb * KSLICE;

    // staging: thread t writes float4 at (row = t>>3, q = t&7) and (+32 rows)
    const int sr = tid >> 3;
    const int sq = tid & 7;
    const float* __restrict__ xg0 = x + (rowbase + sr) * (size_t)KDIM + kbase + 4 * sq;
    const float* __restrict__ xg1 = xg0 + (size_t)32 * KDIM;

    float acc[ODIM];
    #pragma unroll
    for (int o = 0; o < ODIM; ++o) acc[o] = 0.f;

    // prologue: tile 0 -> buf0
    float4 v0 = *(const float4*)xg0;
    float4 v1 = *(const float4*)xg1;
    *(float4*)&sm.buf[0][sr][4 * sq]      = v0;
    *(float4*)&sm.buf[0][sr + 32][4 * sq] = v1;

    const float* __restrict__ wb = bwT + (size_t)(kbase + wv * 8) * ODIM;

    for (int t = 0; t < NTILE; ++t) {
        float4 n0, n1;
        if (t + 1 < NTILE) {
            n0 = *(const float4*)(xg0 + (t + 1) * KT);
            n1 = *(const float4*)(xg1 + (t + 1) * KT);
        }

        __syncthreads();   // buf[t&1] fully written; buf[(t+1)&1] free

        // this wave's 8 k's of the tile: two structural-floor ds_read_b128
        const float4 xk0 = *(const float4*)&sm.buf[t & 1][lane][wv * 8];
        const float4 xk1 = *(const float4*)&sm.buf[t & 1][lane][wv * 8 + 4];

        if (t + 1 < NTILE) {
            *(float4*)&sm.buf[(t + 1) & 1][sr][4 * sq]      = n0;
            *(float4*)&sm.buf[(t + 1) & 1][sr + 32][4 * sq] = n1;
        }

        const float xs[8] = {xk0.x, xk0.y, xk0.z, xk0.w,
                             xk1.x, xk1.y, xk1.z, xk1.w};
        const float* __restrict__ wt = wb + (size_t)t * KT * ODIM;
        #pragma unroll
        for (int kk = 0; kk < 8; ++kk) {
            const float* __restrict__ wo = wt + kk * ODIM;   // wave-uniform
            #pragma unroll
            for (int o = 0; o < ODIM; ++o)
                acc[o] = fmaf(xs[kk], wo[o], acc[o]);
        }
    }

    // two-phase cross-wave reduce (fits union)
    __syncthreads();
    if (wv < 2) {
        #pragma unroll
        for (int o = 0; o < ODIM; ++o) sm.part[wv][o][lane] = acc[o];
    }
    __syncthreads();
    if (wv >= 2) {
        #pragma unroll
        for (int o = 0; o < ODIM; ++o) sm.part[wv - 2][o][lane] += acc[o];
    }
    __syncthreads();

    float* __restrict__ pb = pout + ((size_t)kb * BATCH + rowbase) * ODIM;
    #pragma unroll
    for (int i = 0; i < 8; ++i) {
        int j = tid + THREADS * i;        // j = r*32 + o, fully coalesced
        int r = j >> 5, o = j & 31;
        pb[j] = sm.part[0][o][r] + sm.part[1][o][r];
    }
}

// ---------------------------------------------------------------------------
// Final: recompute scale from the 1024 |w| partials (L2-hot, deterministic),
// then out = (sum of 8 split-K partials) * scale. Grid 512 x 256.
// ---------------------------------------------------------------------------
__global__ void reduce_kernel(const float* __restrict__ pout,
                              const float* __restrict__ partial,
                              float* __restrict__ out) {
    const int t = threadIdx.x;
    float a = (partial[t] + partial[t + 256]) + (partial[t + 512] + partial[t + 768]);
    #pragma unroll
    for (int off = 32; off; off >>= 1) a += __shfl_down(a, off, 64);
    __shared__ float red[4];
    __shared__ float sbc;
    if ((t & 63) == 0) red[t >> 6] = a;
    __syncthreads();
    if (t == 0)
        sbc = ((red[0] + red[1]) + (red[2] + red[3])) / (float)(ODIM * KDIM);
    __syncthreads();
    const float s = sbc;

    const int STRIDE = BATCH * ODIM / 4;          // float4 per split slice
    int i = blockIdx.x * 256 + t;
    const float4* p = (const float4*)pout;
    float4 r = p[i];
    #pragma unroll
    for (int k = 1; k < SK; ++k) {
        float4 A = p[i + k * STRIDE];
        r.x += A.x; r.y += A.y; r.z += A.z; r.w += A.w;
    }
    r.x *= s; r.y *= s; r.z *= s; r.w *= s;
    ((float4*)out)[i] = r;
}

// ---------------------------------------------------------------------------
extern "C" void kernel_launch(void* const* d_in, const int* in_sizes, int n_in,
                              void* d_out, int out_size, void* d_ws, size_t ws_size,
                              hipStream_t stream) {
    const float* x = (const float*)d_in[0];
    const float* w = (const float*)d_in[1];
    float* out = (float*)d_out;

    float* wsf     = (float*)d_ws;
    float* partial = wsf;                       // 1024 floats
    float* bwT     = wsf + 1024;                // 262144 floats (1 MiB), [k][o]
    float* pout    = wsf + 1024 + ODIM * KDIM;  // SK * 524288 floats (16 MiB)

    prep_kernel<<<1024, 256, 0, stream>>>(w, bwT, partial);
    main_kernel<<<256 * SK, THREADS, 0, stream>>>(x, bwT, pout);
    reduce_kernel<<<BATCH * ODIM / 4 / 256, 256, 0, stream>>>(pout, partial, out);
}